// Round 2
// baseline (2072.322 us; speedup 1.0000x reference)
//
#include <hip/hip_runtime.h>

typedef unsigned int u32;

#define NN 100000
#define NE 3200000
#define NB 256
#define FTD 41
#define DIM 32

// ---------------- drug branch: conv1d (NCH, OIH, valid) ----------------
// e[b,i,hh] = emb[xd[b,i], hh]  (i=0..99 channels, hh=0..127 positions)
// c[b,o,h] = sum_{i,k} e[b,i,h+k] * w[o,i,k] + convb[o],  h=0..120, o=0..31
// grid: 256 b * 8 o-groups (4 o each)
__global__ __launch_bounds__(256) void k_conv(
    const int* __restrict__ xd, const float* __restrict__ emb,
    const float* __restrict__ convw, const float* __restrict__ convb,
    float* __restrict__ C) {
  __shared__ float e_s[100 * 128];
  __shared__ float w_s[4 * 800];
  __shared__ int xd_s[100];
  int t = threadIdx.x;
  int b = blockIdx.x >> 3;
  int og = (blockIdx.x & 7) << 2;
  if (t < 100) xd_s[t] = xd[b * 100 + t];
  __syncthreads();
  for (int i = t; i < 12800; i += 256)
    e_s[i] = emb[xd_s[i >> 7] * 128 + (i & 127)];
  for (int i = t; i < 3200; i += 256)
    w_s[i] = convw[og * 800 + i];
  __syncthreads();
  for (int idx = t; idx < 484; idx += 256) {
    int o = idx / 121, h = idx - o * 121;
    const float* wp = &w_s[o * 800];
    const float* ep = &e_s[h];
    float acc = 0.f;
    for (int i = 0; i < 100; i++) {
#pragma unroll
      for (int k = 0; k < 8; k++) acc += ep[i * 128 + k] * wp[i * 8 + k];
    }
    C[b * 3872 + (og + o) * 121 + h] = acc + convb[og + o];
  }
}

// xd_f[b,j] = sum_k C[b,k] * fcdw[k,j] + fcdb[j]   (k=0..3871, j=0..127)
__global__ __launch_bounds__(256) void k_fcd(
    const float* __restrict__ C, const float* __restrict__ fcdw,
    const float* __restrict__ fcdb, float* __restrict__ XJ) {
  __shared__ float c_s[3872];
  __shared__ float red[128];
  int t = threadIdx.x, b = blockIdx.x;
  for (int i = t; i < 3872; i += 256) c_s[i] = C[b * 3872 + i];
  __syncthreads();
  int j = t & 127, half = t >> 7;
  float acc = 0.f;
  int k0 = half * 1936;
  for (int k = k0; k < k0 + 1936; k++) acc += c_s[k] * fcdw[k * 128 + j];
  if (half) red[j] = acc;
  __syncthreads();
  if (!half) XJ[b * 256 + j] = acc + red[j] + fcdb[j];
}

// ---------------- protein branch ----------------
// Z[n] = xt[n] @ g1_w1  (41->32); AGG[n] = Z[n]. Also zeros POOL.
__global__ __launch_bounds__(256) void k_z1(
    const float* __restrict__ xt, const float* __restrict__ w1,
    float* __restrict__ Z, float* __restrict__ AGG, float* __restrict__ pool) {
  __shared__ float xs[256 * FTD];
  __shared__ float w1s[FTD * DIM];
  int t = threadIdx.x;
  int base = blockIdx.x * 256;
  int g = base + t;
  if (g < NB * DIM) pool[g] = 0.f;
  for (int i = t; i < FTD * DIM; i += 256) w1s[i] = w1[i];
  int cnt = min(256, NN - base);
  for (int i = t; i < cnt * FTD; i += 256) xs[i] = xt[base * FTD + i];
  __syncthreads();
  int n = base + t;
  if (n < NN) {
    float acc[DIM];
#pragma unroll
    for (int j = 0; j < DIM; j++) acc[j] = 0.f;
    for (int k = 0; k < FTD; k++) {
      float xk = xs[t * FTD + k];
#pragma unroll
      for (int j = 0; j < DIM; j++) acc[j] += xk * w1s[k * DIM + j];
    }
    float* zp = &Z[n * DIM];
    float* ap = &AGG[n * DIM];
#pragma unroll
    for (int j = 0; j < DIM; j++) { zp[j] = acc[j]; ap[j] = acc[j]; }
  }
}

// AGG[dst] += Z[src] for each edge; 32 lanes per edge (feature-major).
__global__ __launch_bounds__(256) void k_scatter(
    const int* __restrict__ ei, const float* __restrict__ Z,
    float* __restrict__ AGG) {
  int gid = blockIdx.x * 256 + threadIdx.x;
  int e = gid >> 5, f = gid & 31;
  int s = ei[e], d = ei[NE + e];
  atomicAdd(&AGG[d * DIM + f], Z[s * DIM + f]);
}

// node MLP: hid = relu(AGG[n] + b1); out = hid@w2 + b2; hn = bn(relu(out));
// if HAS_NEXT: Z[n] = AGG[n] = hn @ w1_next.  if DO_POOL: pool[batch[n]] += hn.
template <int HAS_NEXT, int DO_POOL>
__global__ __launch_bounds__(256) void k_node(
    const float* __restrict__ b1, const float* __restrict__ w2,
    const float* __restrict__ b2, const float* __restrict__ bng,
    const float* __restrict__ bnb, const float* __restrict__ bnrm,
    const float* __restrict__ bnrv, const float* __restrict__ w1n,
    float* AGG, float* __restrict__ Z, float* __restrict__ pool,
    const int* __restrict__ batch) {
  __shared__ float w2s[DIM * DIM];
  __shared__ float w1ns[DIM * DIM];
  __shared__ float b1s[DIM], b2s[DIM], scs[DIM], shs[DIM];
  int t = threadIdx.x;
  for (int i = t; i < DIM * DIM; i += 256) {
    w2s[i] = w2[i];
    if (HAS_NEXT) w1ns[i] = w1n[i];
  }
  if (t < DIM) {
    b1s[t] = b1[t];
    b2s[t] = b2[t];
    float gg = bng[t], bb = bnb[t];
    float rm = bnrm[t], rv = bnrv[t];
    float sc = gg * rsqrtf(rv + 1e-5f);
    scs[t] = sc;
    shs[t] = bb - rm * sc;
  }
  __syncthreads();
  int n = blockIdx.x * 256 + t;
  float hn[DIM];
  if (n < NN) {
    const float* ar = &AGG[n * DIM];
    float hid[DIM];
#pragma unroll
    for (int j = 0; j < DIM; j++) hid[j] = fmaxf(ar[j] + b1s[j], 0.f);
    float acc[DIM];
#pragma unroll
    for (int j = 0; j < DIM; j++) acc[j] = b2s[j];
#pragma unroll
    for (int k = 0; k < DIM; k++) {
      float hk = hid[k];
#pragma unroll
      for (int j = 0; j < DIM; j++) acc[j] += hk * w2s[k * DIM + j];
    }
#pragma unroll
    for (int j = 0; j < DIM; j++) hn[j] = fmaxf(acc[j], 0.f) * scs[j] + shs[j];
    if (HAS_NEXT) {
      float zn[DIM];
#pragma unroll
      for (int j = 0; j < DIM; j++) zn[j] = 0.f;
#pragma unroll
      for (int k = 0; k < DIM; k++) {
        float hk = hn[k];
#pragma unroll
        for (int j = 0; j < DIM; j++) zn[j] += hk * w1ns[k * DIM + j];
      }
      float* zp = &Z[n * DIM];
      float* ap = &AGG[n * DIM];
#pragma unroll
      for (int j = 0; j < DIM; j++) { zp[j] = zn[j]; ap[j] = zn[j]; }
    }
  }
  if (DO_POOL) {
    __shared__ float lp[NB * DIM];
    __shared__ int sblo;
    int base = blockIdx.x * 256;
    if (t == 0) sblo = batch[base];
    __syncthreads();
    int blo = sblo;
    int lastn = min(base + 255, NN - 1);
    int r = batch[lastn] - blo + 1;
    for (int i = t; i < r * DIM; i += 256) lp[i] = 0.f;
    __syncthreads();
    if (n < NN) {
      int bb = (batch[n] - blo) * DIM;
#pragma unroll
      for (int j = 0; j < DIM; j++) atomicAdd(&lp[bb + j], hn[j]);
    }
    __syncthreads();
    for (int i = t; i < r * DIM; i += 256) atomicAdd(&pool[blo * DIM + i], lp[i]);
  }
}

// xt_f[b,j] = relu(pool[b]@fctw + fctb)[j], j=0..127 -> XJ[b,128+j]
__global__ __launch_bounds__(128) void k_fct(
    const float* __restrict__ pool, const float* __restrict__ fctw,
    const float* __restrict__ fctb, float* __restrict__ XJ) {
  __shared__ float p_s[DIM];
  int t = threadIdx.x, b = blockIdx.x;
  if (t < DIM) p_s[t] = pool[b * DIM + t];
  __syncthreads();
  float acc = fctb[t];
  for (int k = 0; k < DIM; k++) acc += p_s[k] * fctw[k * 128 + t];
  XJ[b * 256 + 128 + t] = fmaxf(acc, 0.f);
}

// H1[b,j] = relu(XJ[b]@c1w + c1b), j tile of 256 per block (grid 4 x 256)
__global__ __launch_bounds__(256) void k_c1(
    const float* __restrict__ XJ, const float* __restrict__ w,
    const float* __restrict__ bias, float* __restrict__ H1) {
  __shared__ float xs[256];
  int t = threadIdx.x, b = blockIdx.y;
  xs[t] = XJ[b * 256 + t];
  __syncthreads();
  int j = blockIdx.x * 256 + t;
  float acc = bias[j];
  for (int k = 0; k < 256; k++) acc += xs[k] * w[k * 1024 + j];
  H1[b * 1024 + j] = fmaxf(acc, 0.f);
}

// H2[b,j] = relu(H1[b]@c2w + c2b)
__global__ __launch_bounds__(256) void k_c2(
    const float* __restrict__ H1, const float* __restrict__ w,
    const float* __restrict__ bias, float* __restrict__ H2) {
  __shared__ float hs[1024];
  int t = threadIdx.x, b = blockIdx.x;
  for (int i = t; i < 1024; i += 256) hs[i] = H1[b * 1024 + i];
  __syncthreads();
  float acc = bias[t];
  for (int k = 0; k < 1024; k++) acc += hs[k] * w[k * 256 + t];
  H2[b * 256 + t] = fmaxf(acc, 0.f);
}

// out[b] = H2[b]@c3w + c3b; also pass through y.
__global__ __launch_bounds__(64) void k_c3(
    const float* __restrict__ H2, const float* __restrict__ w,
    const float* __restrict__ bias, const float* __restrict__ y,
    float* __restrict__ out) {
  int b = blockIdx.x * 64 + threadIdx.x;
  float acc = bias[0];
  for (int k = 0; k < 256; k++) acc += H2[b * 256 + k] * w[k];
  out[b] = acc;
  out[NB + b] = y[b];
}

extern "C" void kernel_launch(void* const* d_in, const int* in_sizes, int n_in,
                              void* d_out, int out_size, void* d_ws,
                              size_t ws_size, hipStream_t stream) {
  const int* xd = (const int*)d_in[0];
  const float* xt = (const float*)d_in[1];
  const int* ei = (const int*)d_in[2];
  const int* batch = (const int*)d_in[3];
  const float* y = (const float*)d_in[4];
  const float* emb = (const float*)d_in[5];
  const float* convw = (const float*)d_in[6];
  const float* convb = (const float*)d_in[7];
  const float* fcdw = (const float*)d_in[8];
  const float* fcdb = (const float*)d_in[9];
  const float* g1w1 = (const float*)d_in[10];
  const float* g1b1 = (const float*)d_in[11];
  const float* g1w2 = (const float*)d_in[12];
  const float* g1b2 = (const float*)d_in[13];
  const float* gw1 = (const float*)d_in[14];
  const float* gb1 = (const float*)d_in[15];
  const float* gw2 = (const float*)d_in[16];
  const float* gb2 = (const float*)d_in[17];
  const float* bng = (const float*)d_in[18];
  const float* bnb = (const float*)d_in[19];
  const float* bnrm = (const float*)d_in[20];
  const float* bnrv = (const float*)d_in[21];
  const float* fctw = (const float*)d_in[22];
  const float* fctb = (const float*)d_in[23];
  const float* c1w = (const float*)d_in[24];
  const float* c1b = (const float*)d_in[25];
  const float* c2w = (const float*)d_in[26];
  const float* c2b = (const float*)d_in[27];
  const float* c3w = (const float*)d_in[28];
  const float* c3b = (const float*)d_in[29];
  float* out = (float*)d_out;

  float* ws = (float*)d_ws;
  float* Z = ws;                          // N*32
  float* AGG = Z + (size_t)NN * DIM;      // N*32
  float* C = AGG + (size_t)NN * DIM;      // 256*3872
  float* XJ = C + (size_t)NB * 3872;      // 256*256
  float* H1 = XJ + NB * 256;              // 256*1024
  float* H2 = H1 + NB * 1024;             // 256*256
  float* POOL = H2 + NB * 256;            // 256*32

  int nblk = (NN + 255) / 256;

  k_conv<<<NB * 8, 256, 0, stream>>>(xd, emb, convw, convb, C);
  k_fcd<<<NB, 256, 0, stream>>>(C, fcdw, fcdb, XJ);
  k_z1<<<nblk, 256, 0, stream>>>(xt, g1w1, Z, AGG, POOL);
  for (int i = 0; i < 5; i++) {
    k_scatter<<<NE * 32 / 256, 256, 0, stream>>>(ei, Z, AGG);
    const float *b1, *w2, *b2;
    if (i == 0) { b1 = g1b1; w2 = g1w2; b2 = g1b2; }
    else {
      b1 = gb1 + (i - 1) * DIM;
      w2 = gw2 + (i - 1) * DIM * DIM;
      b2 = gb2 + (i - 1) * DIM;
    }
    const float* w1n = (i < 4) ? (gw1 + i * DIM * DIM) : (const float*)nullptr;
    if (i < 4)
      k_node<1, 0><<<nblk, 256, 0, stream>>>(b1, w2, b2, bng + i * DIM,
                                             bnb + i * DIM, bnrm + i * DIM,
                                             bnrv + i * DIM, w1n, AGG, Z, POOL,
                                             batch);
    else
      k_node<0, 1><<<nblk, 256, 0, stream>>>(b1, w2, b2, bng + i * DIM,
                                             bnb + i * DIM, bnrm + i * DIM,
                                             bnrv + i * DIM, w1n, AGG, Z, POOL,
                                             batch);
  }
  k_fct<<<NB, 128, 0, stream>>>(POOL, fctw, fctb, XJ);
  k_c1<<<dim3(4, NB), 256, 0, stream>>>(XJ, c1w, c1b, H1);
  k_c2<<<NB, 256, 0, stream>>>(H1, c2w, c2b, H2);
  k_c3<<<4, 64, 0, stream>>>(H2, c3w, c3b, y, out);
}

// Round 3
// 1568.331 us; speedup vs baseline: 1.3214x; 1.3214x over previous
//
#include <hip/hip_runtime.h>

typedef unsigned int u32;

#define NN 100000
#define NE 3200000
#define NB 256
#define FTD 41
#define DIM 32

// ---------------- CSR build ----------------
__global__ __launch_bounds__(256) void k_init(int* __restrict__ cnt,
                                              int* __restrict__ cur) {
  int g = blockIdx.x * 256 + threadIdx.x;
  if (g < NN) { cnt[g] = 0; cur[g] = 0; }
}

__global__ __launch_bounds__(256) void k_hist(const int* __restrict__ ei,
                                              int* __restrict__ cnt) {
  int g = blockIdx.x * 256 + threadIdx.x;
  atomicAdd(&cnt[ei[NE + g]], 1);
}

// single-block exclusive scan of cnt[0..NN-1] -> off[0..NN]
__global__ __launch_bounds__(1024) void k_scan(const int* __restrict__ cnt,
                                               int* __restrict__ off) {
  __shared__ int sm[1024];
  int t = threadIdx.x;
  const int CH = 98;  // 1024*98 = 100352 >= 100001
  int a = t * CH;
  int local = 0;
  for (int j = a; j < a + CH && j < NN; j++) local += cnt[j];
  sm[t] = local;
  __syncthreads();
  for (int d = 1; d < 1024; d <<= 1) {
    int v = (t >= d) ? sm[t - d] : 0;
    __syncthreads();
    sm[t] += v;
    __syncthreads();
  }
  int running = sm[t] - local;  // exclusive base
  for (int j = a; j < a + CH && j <= NN; j++) {
    off[j] = running;
    if (j < NN) running += cnt[j];
  }
}

__global__ __launch_bounds__(256) void k_fill(const int* __restrict__ ei,
                                              const int* __restrict__ off,
                                              int* __restrict__ cur,
                                              int* __restrict__ srcs) {
  int g = blockIdx.x * 256 + threadIdx.x;
  int s = ei[g], d = ei[NE + g];
  int pos = atomicAdd(&cur[d], 1);
  srcs[off[d] + pos] = s;
}

// ---------------- drug branch ----------------
__global__ __launch_bounds__(256) void k_conv(
    const int* __restrict__ xd, const float* __restrict__ emb,
    const float* __restrict__ convw, const float* __restrict__ convb,
    float* __restrict__ C) {
  __shared__ float e_s[100 * 128];
  __shared__ float w_s[4 * 800];
  __shared__ int xd_s[100];
  int t = threadIdx.x;
  int b = blockIdx.x >> 3;
  int og = (blockIdx.x & 7) << 2;
  if (t < 100) xd_s[t] = xd[b * 100 + t];
  __syncthreads();
  for (int i = t; i < 12800; i += 256)
    e_s[i] = emb[xd_s[i >> 7] * 128 + (i & 127)];
  for (int i = t; i < 3200; i += 256) w_s[i] = convw[og * 800 + i];
  __syncthreads();
  for (int idx = t; idx < 484; idx += 256) {
    int o = idx / 121, h = idx - o * 121;
    const float* wp = &w_s[o * 800];
    const float* ep = &e_s[h];
    float acc = 0.f;
    for (int i = 0; i < 100; i++) {
#pragma unroll
      for (int k = 0; k < 8; k++) acc += ep[i * 128 + k] * wp[i * 8 + k];
    }
    C[b * 3872 + (og + o) * 121 + h] = acc + convb[og + o];
  }
}

__global__ __launch_bounds__(256) void k_fcd(
    const float* __restrict__ C, const float* __restrict__ fcdw,
    const float* __restrict__ fcdb, float* __restrict__ XJ) {
  __shared__ float c_s[3872];
  __shared__ float red[128];
  int t = threadIdx.x, b = blockIdx.x;
  for (int i = t; i < 3872; i += 256) c_s[i] = C[b * 3872 + i];
  __syncthreads();
  int j = t & 127, half = t >> 7;
  float acc = 0.f;
  int k0 = half * 1936;
  for (int k = k0; k < k0 + 1936; k++) acc += c_s[k] * fcdw[k * 128 + j];
  if (half) red[j] = acc;
  __syncthreads();
  if (!half) XJ[b * 256 + j] = acc + red[j] + fcdb[j];
}

// ---------------- protein branch ----------------
// Z0[n] = xt[n] @ g1_w1 (41->32). Also zeros POOL.
__global__ __launch_bounds__(256) void k_z1(
    const float* __restrict__ xt, const float* __restrict__ w1,
    float* __restrict__ Z, float* __restrict__ pool) {
  __shared__ float xs[256 * FTD];
  __shared__ float w1s[FTD * DIM];
  int t = threadIdx.x;
  int base = blockIdx.x * 256;
  int g = base + t;
  if (g < NB * DIM) pool[g] = 0.f;
  for (int i = t; i < FTD * DIM; i += 256) w1s[i] = w1[i];
  int cnt = min(256, NN - base);
  for (int i = t; i < cnt * FTD; i += 256) xs[i] = xt[base * FTD + i];
  __syncthreads();
  int n = base + t;
  if (n < NN) {
    float acc[DIM];
#pragma unroll
    for (int j = 0; j < DIM; j++) acc[j] = 0.f;
    for (int k = 0; k < FTD; k++) {
      float xk = xs[t * FTD + k];
#pragma unroll
      for (int j = 0; j < DIM; j++) acc[j] += xk * w1s[k * DIM + j];
    }
    float* zp = &Z[n * DIM];
#pragma unroll
    for (int j = 0; j < DIM; j++) zp[j] = acc[j];
  }
}

// Fused GIN layer: gather-sum over CSR + node MLP, all per-node in one
// 32-lane group. 8 nodes per 256-thread block; lane f owns feature f.
// agg_f = Zin[n,f] + sum_neighbors Zin[s,f]
// hid = relu(agg + b1); out = hid@w2 + b2; hn = bn(relu(out))
// HAS_NEXT: Zout[n] = hn @ w1next.   DO_POOL: pool[batch[n]] += hn.
template <int HAS_NEXT, int DO_POOL>
__global__ __launch_bounds__(256) void k_gin(
    const int* __restrict__ off, const int* __restrict__ srcs,
    const float* __restrict__ Zin, const float* __restrict__ b1,
    const float* __restrict__ w2, const float* __restrict__ b2,
    const float* __restrict__ bng, const float* __restrict__ bnb,
    const float* __restrict__ bnrm, const float* __restrict__ bnrv,
    const float* __restrict__ w1n, float* __restrict__ Zout,
    float* __restrict__ pool, const int* __restrict__ batch) {
  int t = threadIdx.x;
  int f = t & 31;
  int n = blockIdx.x * 8 + (t >> 5);  // grid*8 == NN exactly
  float w2c[DIM], w1c[DIM];
#pragma unroll
  for (int k = 0; k < DIM; k++) {
    w2c[k] = w2[k * DIM + f];
    if (HAS_NEXT) w1c[k] = w1n[k * DIM + f];
  }
  float b1f = b1[f], b2f = b2[f];
  float sc = bng[f] * rsqrtf(bnrv[f] + 1e-5f);
  float sh = bnb[f] - bnrm[f] * sc;

  int beg = off[n], end = off[n + 1];
  float acc = Zin[n * DIM + f];
  for (int base = beg; base < end; base += 32) {
    int sv = (base + f < end) ? srcs[base + f] : 0;
    int cnt = min(32, end - base);
    for (int k = 0; k < cnt; k++) {
      int s = __shfl(sv, k, 32);
      acc += Zin[s * DIM + f];
    }
  }
  float hid = fmaxf(acc + b1f, 0.f);
  float o = b2f;
#pragma unroll
  for (int k = 0; k < DIM; k++) o += __shfl(hid, k, 32) * w2c[k];
  float hn = fmaxf(o, 0.f) * sc + sh;
  if (HAS_NEXT) {
    float z = 0.f;
#pragma unroll
    for (int k = 0; k < DIM; k++) z += __shfl(hn, k, 32) * w1c[k];
    Zout[n * DIM + f] = z;
  }
  if (DO_POOL) atomicAdd(&pool[batch[n] * DIM + f], hn);
}

// xt_f[b,j] = relu(pool[b]@fctw + fctb)[j] -> XJ[b,128+j]
__global__ __launch_bounds__(128) void k_fct(
    const float* __restrict__ pool, const float* __restrict__ fctw,
    const float* __restrict__ fctb, float* __restrict__ XJ) {
  __shared__ float p_s[DIM];
  int t = threadIdx.x, b = blockIdx.x;
  if (t < DIM) p_s[t] = pool[b * DIM + t];
  __syncthreads();
  float acc = fctb[t];
  for (int k = 0; k < DIM; k++) acc += p_s[k] * fctw[k * 128 + t];
  XJ[b * 256 + 128 + t] = fmaxf(acc, 0.f);
}

__global__ __launch_bounds__(256) void k_c1(
    const float* __restrict__ XJ, const float* __restrict__ w,
    const float* __restrict__ bias, float* __restrict__ H1) {
  __shared__ float xs[256];
  int t = threadIdx.x, b = blockIdx.y;
  xs[t] = XJ[b * 256 + t];
  __syncthreads();
  int j = blockIdx.x * 256 + t;
  float acc = bias[j];
  for (int k = 0; k < 256; k++) acc += xs[k] * w[k * 1024 + j];
  H1[b * 1024 + j] = fmaxf(acc, 0.f);
}

__global__ __launch_bounds__(256) void k_c2(
    const float* __restrict__ H1, const float* __restrict__ w,
    const float* __restrict__ bias, float* __restrict__ H2) {
  __shared__ float hs[1024];
  int t = threadIdx.x, b = blockIdx.x;
  for (int i = t; i < 1024; i += 256) hs[i] = H1[b * 1024 + i];
  __syncthreads();
  float acc = bias[t];
  for (int k = 0; k < 1024; k++) acc += hs[k] * w[k * 256 + t];
  H2[b * 256 + t] = fmaxf(acc, 0.f);
}

__global__ __launch_bounds__(64) void k_c3(
    const float* __restrict__ H2, const float* __restrict__ w,
    const float* __restrict__ bias, const float* __restrict__ y,
    float* __restrict__ out) {
  int b = blockIdx.x * 64 + threadIdx.x;
  float acc = bias[0];
  for (int k = 0; k < 256; k++) acc += H2[b * 256 + k] * w[k];
  out[b] = acc;
  out[NB + b] = y[b];
}

extern "C" void kernel_launch(void* const* d_in, const int* in_sizes, int n_in,
                              void* d_out, int out_size, void* d_ws,
                              size_t ws_size, hipStream_t stream) {
  const int* xd = (const int*)d_in[0];
  const float* xt = (const float*)d_in[1];
  const int* ei = (const int*)d_in[2];
  const int* batch = (const int*)d_in[3];
  const float* y = (const float*)d_in[4];
  const float* emb = (const float*)d_in[5];
  const float* convw = (const float*)d_in[6];
  const float* convb = (const float*)d_in[7];
  const float* fcdw = (const float*)d_in[8];
  const float* fcdb = (const float*)d_in[9];
  const float* g1w1 = (const float*)d_in[10];
  const float* g1b1 = (const float*)d_in[11];
  const float* g1w2 = (const float*)d_in[12];
  const float* g1b2 = (const float*)d_in[13];
  const float* gw1 = (const float*)d_in[14];
  const float* gb1 = (const float*)d_in[15];
  const float* gw2 = (const float*)d_in[16];
  const float* gb2 = (const float*)d_in[17];
  const float* bng = (const float*)d_in[18];
  const float* bnb = (const float*)d_in[19];
  const float* bnrm = (const float*)d_in[20];
  const float* bnrv = (const float*)d_in[21];
  const float* fctw = (const float*)d_in[22];
  const float* fctb = (const float*)d_in[23];
  const float* c1w = (const float*)d_in[24];
  const float* c1b = (const float*)d_in[25];
  const float* c2w = (const float*)d_in[26];
  const float* c2b = (const float*)d_in[27];
  const float* c3w = (const float*)d_in[28];
  const float* c3b = (const float*)d_in[29];
  float* out = (float*)d_out;

  float* ws = (float*)d_ws;
  float* Z0 = ws;                          // N*32
  float* Z1 = Z0 + (size_t)NN * DIM;       // N*32
  float* C = Z1 + (size_t)NN * DIM;        // 256*3872
  float* XJ = C + (size_t)NB * 3872;       // 256*256
  float* H1 = XJ + NB * 256;               // 256*1024
  float* H2 = H1 + NB * 1024;              // 256*256
  float* POOL = H2 + NB * 256;             // 256*32
  int* cnt = (int*)(POOL + NB * DIM);      // NN
  int* cur = cnt + NN;                     // NN
  int* off = cur + NN;                     // NN+1
  int* srcs = off + NN + 1;                // NE

  int nblk = (NN + 255) / 256;

  // CSR build (edge list is layer-invariant)
  k_init<<<nblk, 256, 0, stream>>>(cnt, cur);
  k_hist<<<NE / 256, 256, 0, stream>>>(ei, cnt);
  k_scan<<<1, 1024, 0, stream>>>(cnt, off);
  k_fill<<<NE / 256, 256, 0, stream>>>(ei, off, cur, srcs);

  // drug branch
  k_conv<<<NB * 8, 256, 0, stream>>>(xd, emb, convw, convb, C);
  k_fcd<<<NB, 256, 0, stream>>>(C, fcdw, fcdb, XJ);

  // protein branch
  k_z1<<<nblk, 256, 0, stream>>>(xt, g1w1, Z0, POOL);
  float* zin = Z0;
  float* zout = Z1;
  for (int i = 0; i < 5; i++) {
    const float *b1, *w2, *b2;
    if (i == 0) { b1 = g1b1; w2 = g1w2; b2 = g1b2; }
    else {
      b1 = gb1 + (i - 1) * DIM;
      w2 = gw2 + (i - 1) * DIM * DIM;
      b2 = gb2 + (i - 1) * DIM;
    }
    const float* w1n = gw1 + i * DIM * DIM;  // only read when i<4
    if (i < 4)
      k_gin<1, 0><<<NN / 8, 256, 0, stream>>>(
          off, srcs, zin, b1, w2, b2, bng + i * DIM, bnb + i * DIM,
          bnrm + i * DIM, bnrv + i * DIM, w1n, zout, POOL, batch);
    else
      k_gin<0, 1><<<NN / 8, 256, 0, stream>>>(
          off, srcs, zin, b1, w2, b2, bng + i * DIM, bnb + i * DIM,
          bnrm + i * DIM, bnrv + i * DIM, w1n, zout, POOL, batch);
    float* tmp = zin; zin = zout; zout = tmp;
  }
  k_fct<<<NB, 128, 0, stream>>>(POOL, fctw, fctb, XJ);
  k_c1<<<dim3(4, NB), 256, 0, stream>>>(XJ, c1w, c1b, H1);
  k_c2<<<NB, 256, 0, stream>>>(H1, c2w, c2b, H2);
  k_c3<<<4, 64, 0, stream>>>(H2, c3w, c3b, y, out);
}

// Round 4
// 1506.633 us; speedup vs baseline: 1.3755x; 1.0410x over previous
//
#include <hip/hip_runtime.h>

typedef unsigned int u32;

#define NN 100000
#define NE 3200000
#define NB 256
#define FTD 41
#define DIM 32
#define NBK 782  // ceil(NN/128)

// ---------------- bucketed CSR build ----------------
__global__ __launch_bounds__(256) void k_bzero(int* __restrict__ bcnt) {
  int g = blockIdx.x * 256 + threadIdx.x;
  if (g < NBK) bcnt[g] = 0;
}

// per-block LDS histogram of dst buckets, flushed with global atomics
__global__ __launch_bounds__(256) void k_bhist(const int* __restrict__ ei,
                                               int* __restrict__ bcnt) {
  __shared__ int h[NBK];
  int t = threadIdx.x;
  for (int i = t; i < NBK; i += 256) h[i] = 0;
  __syncthreads();
  for (int g = blockIdx.x * 256 + t; g < NE; g += gridDim.x * 256)
    atomicAdd(&h[ei[NE + g] >> 7], 1);
  __syncthreads();
  for (int i = t; i < NBK; i += 256)
    if (h[i]) atomicAdd(&bcnt[i], h[i]);
}

// exclusive scan of 782 bucket counts; init cursors
__global__ __launch_bounds__(1024) void k_bscan(const int* __restrict__ bcnt,
                                                int* __restrict__ boff,
                                                int* __restrict__ bcur) {
  __shared__ int sm[1024];
  int t = threadIdx.x;
  int v = (t < NBK) ? bcnt[t] : 0;
  sm[t] = v;
  __syncthreads();
  for (int d = 1; d < 1024; d <<= 1) {
    int x = (t >= d) ? sm[t - d] : 0;
    __syncthreads();
    sm[t] += x;
    __syncthreads();
  }
  if (t < NBK) {
    int excl = sm[t] - v;
    boff[t] = excl;
    bcur[t] = excl;
  }
  if (t == 0) boff[NBK] = NE;
}

// scatter edges into bucket-sorted packed array: (dst_local<<20)|src
__global__ __launch_bounds__(256) void k_bscatter(const int* __restrict__ ei,
                                                  int* __restrict__ bcur,
                                                  int* __restrict__ ppack) {
  int g = blockIdx.x * 256 + threadIdx.x;
  int s = ei[g], d = ei[NE + g];
  int pos = atomicAdd(&bcur[d >> 7], 1);
  ppack[pos] = (int)(((u32)(d & 127) << 20) | (u32)s);
}

// one block per bucket: per-node counts -> LDS scan -> off[] + final srcs
__global__ __launch_bounds__(256) void k_bfinal(const int* __restrict__ boff,
                                                const int* __restrict__ ppack,
                                                int* __restrict__ off,
                                                int* __restrict__ srcs) {
  __shared__ int ncnt[128];
  __shared__ int nincl[128];
  int b = blockIdx.x, t = threadIdx.x;
  int e0 = boff[b], e1 = boff[b + 1];
  if (t < 128) ncnt[t] = 0;
  __syncthreads();
  for (int i = e0 + t; i < e1; i += 256) atomicAdd(&ncnt[((u32)ppack[i]) >> 20], 1);
  __syncthreads();
  if (t < 128) nincl[t] = ncnt[t];
  __syncthreads();
  for (int d = 1; d < 128; d <<= 1) {
    int x = 0;
    if (t < 128 && t >= d) x = nincl[t - d];
    __syncthreads();
    if (t < 128) nincl[t] += x;
    __syncthreads();
  }
  int node0 = b * 128;
  if (t < 128) {
    int excl = nincl[t] - ncnt[t];
    int node = node0 + t;
    if (node < NN) off[node] = e0 + excl;
    ncnt[t] = excl;  // becomes cursor (each thread touches only its own slot)
  }
  if (b == 0 && t == 0) off[NN] = NE;
  __syncthreads();
  for (int i = e0 + t; i < e1; i += 256) {
    u32 v = (u32)ppack[i];
    int dl = v >> 20;
    int pos = atomicAdd(&ncnt[dl], 1);
    srcs[e0 + pos] = (int)(v & 0xFFFFF);
  }
}

// ---------------- drug branch ----------------
__global__ __launch_bounds__(256) void k_conv(
    const int* __restrict__ xd, const float* __restrict__ emb,
    const float* __restrict__ convw, const float* __restrict__ convb,
    float* __restrict__ C) {
  __shared__ float e_s[100 * 128];
  __shared__ float w_s[4 * 800];
  __shared__ int xd_s[100];
  int t = threadIdx.x;
  int b = blockIdx.x >> 3;
  int og = (blockIdx.x & 7) << 2;
  if (t < 100) xd_s[t] = xd[b * 100 + t];
  __syncthreads();
  for (int i = t; i < 12800; i += 256)
    e_s[i] = emb[xd_s[i >> 7] * 128 + (i & 127)];
  for (int i = t; i < 3200; i += 256) w_s[i] = convw[og * 800 + i];
  __syncthreads();
  for (int idx = t; idx < 484; idx += 256) {
    int o = idx / 121, h = idx - o * 121;
    const float* wp = &w_s[o * 800];
    const float* ep = &e_s[h];
    float acc = 0.f;
    for (int i = 0; i < 100; i++) {
#pragma unroll
      for (int k = 0; k < 8; k++) acc += ep[i * 128 + k] * wp[i * 8 + k];
    }
    C[b * 3872 + (og + o) * 121 + h] = acc + convb[og + o];
  }
}

__global__ __launch_bounds__(256) void k_fcd(
    const float* __restrict__ C, const float* __restrict__ fcdw,
    const float* __restrict__ fcdb, float* __restrict__ XJ) {
  __shared__ float c_s[3872];
  __shared__ float red[128];
  int t = threadIdx.x, b = blockIdx.x;
  for (int i = t; i < 3872; i += 256) c_s[i] = C[b * 3872 + i];
  __syncthreads();
  int j = t & 127, half = t >> 7;
  float acc = 0.f;
  int k0 = half * 1936;
  for (int k = k0; k < k0 + 1936; k++) acc += c_s[k] * fcdw[k * 128 + j];
  if (half) red[j] = acc;
  __syncthreads();
  if (!half) XJ[b * 256 + j] = acc + red[j] + fcdb[j];
}

// ---------------- protein branch ----------------
__global__ __launch_bounds__(256) void k_z1(
    const float* __restrict__ xt, const float* __restrict__ w1,
    float* __restrict__ Z, float* __restrict__ pool) {
  __shared__ float xs[256 * FTD];
  __shared__ float w1s[FTD * DIM];
  int t = threadIdx.x;
  int base = blockIdx.x * 256;
  int g = base + t;
  if (g < NB * DIM) pool[g] = 0.f;
  for (int i = t; i < FTD * DIM; i += 256) w1s[i] = w1[i];
  int cnt = min(256, NN - base);
  for (int i = t; i < cnt * FTD; i += 256) xs[i] = xt[base * FTD + i];
  __syncthreads();
  int n = base + t;
  if (n < NN) {
    float acc[DIM];
#pragma unroll
    for (int j = 0; j < DIM; j++) acc[j] = 0.f;
    for (int k = 0; k < FTD; k++) {
      float xk = xs[t * FTD + k];
#pragma unroll
      for (int j = 0; j < DIM; j++) acc[j] += xk * w1s[k * DIM + j];
    }
    float* zp = &Z[n * DIM];
#pragma unroll
    for (int j = 0; j < DIM; j++) zp[j] = acc[j];
  }
}

// Fused GIN layer: 32 lanes per node, lane f owns feature f.
// Gather in fixed 32-iteration chunks with 4 accumulators (deep ILP).
template <int HAS_NEXT, int DO_POOL>
__global__ __launch_bounds__(256) void k_gin(
    const int* __restrict__ off, const int* __restrict__ srcs,
    const float* __restrict__ Zin, const float* __restrict__ b1,
    const float* __restrict__ w2, const float* __restrict__ b2,
    const float* __restrict__ bng, const float* __restrict__ bnb,
    const float* __restrict__ bnrm, const float* __restrict__ bnrv,
    const float* __restrict__ w1n, float* __restrict__ Zout,
    float* __restrict__ pool, const int* __restrict__ batch) {
  int t = threadIdx.x;
  int f = t & 31;
  int n = blockIdx.x * 8 + (t >> 5);  // grid*8 == NN exactly
  int beg = off[n], end = off[n + 1];
  float a0 = Zin[n * DIM + f], a1 = 0.f, a2 = 0.f, a3 = 0.f;
  for (int base = beg; base < end; base += 32) {
    int idx = base + f;
    int sv = (idx < end) ? srcs[idx] : -1;
#pragma unroll
    for (int k = 0; k < 32; k += 4) {
      int s0 = __shfl(sv, k, 32);
      int s1 = __shfl(sv, k + 1, 32);
      int s2 = __shfl(sv, k + 2, 32);
      int s3 = __shfl(sv, k + 3, 32);
      float v0 = Zin[max(s0, 0) * DIM + f];
      float v1 = Zin[max(s1, 0) * DIM + f];
      float v2 = Zin[max(s2, 0) * DIM + f];
      float v3 = Zin[max(s3, 0) * DIM + f];
      a0 += (s0 >= 0) ? v0 : 0.f;
      a1 += (s1 >= 0) ? v1 : 0.f;
      a2 += (s2 >= 0) ? v2 : 0.f;
      a3 += (s3 >= 0) ? v3 : 0.f;
    }
  }
  float acc = (a0 + a1) + (a2 + a3);
  float hid = fmaxf(acc + b1[f], 0.f);
  float o = b2[f];
#pragma unroll
  for (int k = 0; k < DIM; k++) o += __shfl(hid, k, 32) * w2[k * DIM + f];
  float sc = bng[f] * rsqrtf(bnrv[f] + 1e-5f);
  float hn = fmaxf(o, 0.f) * sc + (bnb[f] - bnrm[f] * sc);
  if (HAS_NEXT) {
    float z = 0.f;
#pragma unroll
    for (int k = 0; k < DIM; k++) z += __shfl(hn, k, 32) * w1n[k * DIM + f];
    Zout[n * DIM + f] = z;
  }
  if (DO_POOL) atomicAdd(&pool[batch[n] * DIM + f], hn);
}

__global__ __launch_bounds__(128) void k_fct(
    const float* __restrict__ pool, const float* __restrict__ fctw,
    const float* __restrict__ fctb, float* __restrict__ XJ) {
  __shared__ float p_s[DIM];
  int t = threadIdx.x, b = blockIdx.x;
  if (t < DIM) p_s[t] = pool[b * DIM + t];
  __syncthreads();
  float acc = fctb[t];
  for (int k = 0; k < DIM; k++) acc += p_s[k] * fctw[k * 128 + t];
  XJ[b * 256 + 128 + t] = fmaxf(acc, 0.f);
}

__global__ __launch_bounds__(256) void k_c1(
    const float* __restrict__ XJ, const float* __restrict__ w,
    const float* __restrict__ bias, float* __restrict__ H1) {
  __shared__ float xs[256];
  int t = threadIdx.x, b = blockIdx.y;
  xs[t] = XJ[b * 256 + t];
  __syncthreads();
  int j = blockIdx.x * 256 + t;
  float acc = bias[j];
  for (int k = 0; k < 256; k++) acc += xs[k] * w[k * 1024 + j];
  H1[b * 1024 + j] = fmaxf(acc, 0.f);
}

__global__ __launch_bounds__(256) void k_c2(
    const float* __restrict__ H1, const float* __restrict__ w,
    const float* __restrict__ bias, float* __restrict__ H2) {
  __shared__ float hs[1024];
  int t = threadIdx.x, b = blockIdx.x;
  for (int i = t; i < 1024; i += 256) hs[i] = H1[b * 1024 + i];
  __syncthreads();
  float acc = bias[t];
  for (int k = 0; k < 1024; k++) acc += hs[k] * w[k * 256 + t];
  H2[b * 256 + t] = fmaxf(acc, 0.f);
}

__global__ __launch_bounds__(64) void k_c3(
    const float* __restrict__ H2, const float* __restrict__ w,
    const float* __restrict__ bias, const float* __restrict__ y,
    float* __restrict__ out) {
  int b = blockIdx.x * 64 + threadIdx.x;
  float acc = bias[0];
  for (int k = 0; k < 256; k++) acc += H2[b * 256 + k] * w[k];
  out[b] = acc;
  out[NB + b] = y[b];
}

extern "C" void kernel_launch(void* const* d_in, const int* in_sizes, int n_in,
                              void* d_out, int out_size, void* d_ws,
                              size_t ws_size, hipStream_t stream) {
  const int* xd = (const int*)d_in[0];
  const float* xt = (const float*)d_in[1];
  const int* ei = (const int*)d_in[2];
  const int* batch = (const int*)d_in[3];
  const float* y = (const float*)d_in[4];
  const float* emb = (const float*)d_in[5];
  const float* convw = (const float*)d_in[6];
  const float* convb = (const float*)d_in[7];
  const float* fcdw = (const float*)d_in[8];
  const float* fcdb = (const float*)d_in[9];
  const float* g1w1 = (const float*)d_in[10];
  const float* g1b1 = (const float*)d_in[11];
  const float* g1w2 = (const float*)d_in[12];
  const float* g1b2 = (const float*)d_in[13];
  const float* gw1 = (const float*)d_in[14];
  const float* gb1 = (const float*)d_in[15];
  const float* gw2 = (const float*)d_in[16];
  const float* gb2 = (const float*)d_in[17];
  const float* bng = (const float*)d_in[18];
  const float* bnb = (const float*)d_in[19];
  const float* bnrm = (const float*)d_in[20];
  const float* bnrv = (const float*)d_in[21];
  const float* fctw = (const float*)d_in[22];
  const float* fctb = (const float*)d_in[23];
  const float* c1w = (const float*)d_in[24];
  const float* c1b = (const float*)d_in[25];
  const float* c2w = (const float*)d_in[26];
  const float* c2b = (const float*)d_in[27];
  const float* c3w = (const float*)d_in[28];
  const float* c3b = (const float*)d_in[29];
  float* out = (float*)d_out;

  float* ws = (float*)d_ws;
  float* Z0 = ws;                            // NN*32 f32
  float* Z1 = Z0 + (size_t)NN * DIM;         // NN*32 f32
  int* srcs = (int*)(Z1 + (size_t)NN * DIM); // NE int
  int* off = srcs + NE;                      // NN+1
  int* bcnt = off + NN + 1;                  // NBK
  int* boff = bcnt + NBK;                    // NBK+1
  int* bcur = boff + NBK + 1;                // NBK
  // union region: ppack (CSR build) aliases drug/classifier temps
  // (safe: all launches below are stream-ordered; ppack dead after k_bfinal)
  int* ppack = bcur + NBK;                   // NE int
  float* C = (float*)ppack;                  // 256*3872
  float* XJ = C + (size_t)NB * 3872;         // 256*256
  float* H1 = XJ + NB * 256;                 // 256*1024
  float* H2 = H1 + NB * 1024;                // 256*256
  float* POOL = H2 + NB * 256;               // 256*32

  int nblk = (NN + 255) / 256;

  // CSR build (edge list is layer-invariant)
  k_bzero<<<(NBK + 255) / 256, 256, 0, stream>>>(bcnt);
  k_bhist<<<512, 256, 0, stream>>>(ei, bcnt);
  k_bscan<<<1, 1024, 0, stream>>>(bcnt, boff, bcur);
  k_bscatter<<<NE / 256, 256, 0, stream>>>(ei, bcur, ppack);
  k_bfinal<<<NBK, 256, 0, stream>>>(boff, ppack, off, srcs);

  // drug branch (reuses ppack region — after k_bfinal, stream-ordered)
  k_conv<<<NB * 8, 256, 0, stream>>>(xd, emb, convw, convb, C);
  k_fcd<<<NB, 256, 0, stream>>>(C, fcdw, fcdb, XJ);

  // protein branch
  k_z1<<<nblk, 256, 0, stream>>>(xt, g1w1, Z0, POOL);
  float* zin = Z0;
  float* zout = Z1;
  for (int i = 0; i < 5; i++) {
    const float *b1, *w2, *b2;
    if (i == 0) { b1 = g1b1; w2 = g1w2; b2 = g1b2; }
    else {
      b1 = gb1 + (i - 1) * DIM;
      w2 = gw2 + (i - 1) * DIM * DIM;
      b2 = gb2 + (i - 1) * DIM;
    }
    const float* w1n = gw1 + i * DIM * DIM;  // only read when i<4
    if (i < 4)
      k_gin<1, 0><<<NN / 8, 256, 0, stream>>>(
          off, srcs, zin, b1, w2, b2, bng + i * DIM, bnb + i * DIM,
          bnrm + i * DIM, bnrv + i * DIM, w1n, zout, POOL, batch);
    else
      k_gin<0, 1><<<NN / 8, 256, 0, stream>>>(
          off, srcs, zin, b1, w2, b2, bng + i * DIM, bnb + i * DIM,
          bnrm + i * DIM, bnrv + i * DIM, w1n, zout, POOL, batch);
    float* tmp = zin; zin = zout; zout = tmp;
  }
  k_fct<<<NB, 128, 0, stream>>>(POOL, fctw, fctb, XJ);
  k_c1<<<dim3(4, NB), 256, 0, stream>>>(XJ, c1w, c1b, H1);
  k_c2<<<NB, 256, 0, stream>>>(H1, c2w, c2b, H2);
  k_c3<<<4, 64, 0, stream>>>(H2, c3w, c3b, y, out);
}

// Round 5
// 810.118 us; speedup vs baseline: 2.5580x; 1.8598x over previous
//
#include <hip/hip_runtime.h>

typedef unsigned int u32;

#define NN 100000
#define NE 3200000
#define NB 256
#define FTD 41
#define DIM 32
#define NBK 782    // ceil(NN/128)
#define SCHUNK 8000  // edges per k_bscatter block; 400*8000 == NE

// ---------------- bucketed CSR build ----------------
__global__ __launch_bounds__(256) void k_bzero(int* __restrict__ bcnt) {
  int g = blockIdx.x * 256 + threadIdx.x;
  if (g < NBK) bcnt[g] = 0;
}

// per-block LDS histogram of dst buckets, flushed with global atomics
__global__ __launch_bounds__(256) void k_bhist(const int* __restrict__ ei,
                                               int* __restrict__ bcnt) {
  __shared__ int h[NBK];
  int t = threadIdx.x;
  for (int i = t; i < NBK; i += 256) h[i] = 0;
  __syncthreads();
  for (int g = blockIdx.x * 256 + t; g < NE; g += gridDim.x * 256)
    atomicAdd(&h[ei[NE + g] >> 7], 1);
  __syncthreads();
  for (int i = t; i < NBK; i += 256)
    if (h[i]) atomicAdd(&bcnt[i], h[i]);
}

// exclusive scan of 782 bucket counts; init cursors
__global__ __launch_bounds__(1024) void k_bscan(const int* __restrict__ bcnt,
                                                int* __restrict__ boff,
                                                int* __restrict__ bcur) {
  __shared__ int sm[1024];
  int t = threadIdx.x;
  int v = (t < NBK) ? bcnt[t] : 0;
  sm[t] = v;
  __syncthreads();
  for (int d = 1; d < 1024; d <<= 1) {
    int x = (t >= d) ? sm[t - d] : 0;
    __syncthreads();
    sm[t] += x;
    __syncthreads();
  }
  if (t < NBK) {
    int excl = sm[t] - v;
    boff[t] = excl;
    bcur[t] = excl;
  }
  if (t == 0) boff[NBK] = NE;
}

// LDS-staged bucket scatter: block sorts SCHUNK edges by bucket in LDS,
// reserves per-bucket global runs with ONE atomic per (block,bucket),
// then flushes linearly (coalesced runs). Output: ppack=(dst_local<<20)|src.
__global__ __launch_bounds__(256) void k_bscatter(const int* __restrict__ ei,
                                                  int* __restrict__ bcur,
                                                  int* __restrict__ ppack) {
  __shared__ int lexcl[NBK];  // counts, then local exclusive offsets
  __shared__ int lcur[NBK];
  __shared__ int gdelta[NBK];
  __shared__ int lbuf[SCHUNK];
  __shared__ unsigned short lbkt[SCHUNK];
  __shared__ int sm[256];
  int t = threadIdx.x;
  int e0 = blockIdx.x * SCHUNK;
  for (int i = t; i < NBK; i += 256) lexcl[i] = 0;
  __syncthreads();
  for (int i = t; i < SCHUNK; i += 256)
    atomicAdd(&lexcl[((u32)ei[NE + e0 + i]) >> 7], 1);
  __syncthreads();
  // scan: thread t owns buckets [4t, 4t+4)
  int b0 = t * 4;
  int c0 = 0, c1 = 0, c2 = 0, c3 = 0;
  if (b0 < NBK) {
    c0 = lexcl[b0];
    c1 = (b0 + 1 < NBK) ? lexcl[b0 + 1] : 0;
    c2 = (b0 + 2 < NBK) ? lexcl[b0 + 2] : 0;
    c3 = (b0 + 3 < NBK) ? lexcl[b0 + 3] : 0;
  }
  int tot = c0 + c1 + c2 + c3;
  sm[t] = tot;
  __syncthreads();
  for (int d = 1; d < 256; d <<= 1) {
    int x = (t >= d) ? sm[t - d] : 0;
    __syncthreads();
    sm[t] += x;
    __syncthreads();
  }
  int base = sm[t] - tot;
  if (b0 < NBK) {
    int cnts[4] = {c0, c1, c2, c3};
    int e = base;
#pragma unroll
    for (int j = 0; j < 4; j++) {
      int b = b0 + j;
      if (b < NBK) {
        int c = cnts[j];
        lexcl[b] = e;
        lcur[b] = e;
        if (c > 0) gdelta[b] = atomicAdd(&bcur[b], c) - e;
        e += c;
      }
    }
  }
  __syncthreads();
  for (int i = t; i < SCHUNK; i += 256) {
    int s = ei[e0 + i];
    u32 d = (u32)ei[NE + e0 + i];
    int b = d >> 7;
    int p = atomicAdd(&lcur[b], 1);
    lbuf[p] = (int)(((d & 127u) << 20) | (u32)s);
    lbkt[p] = (unsigned short)b;
  }
  __syncthreads();
  for (int i = t; i < SCHUNK; i += 256) {
    int b = lbkt[i];
    ppack[gdelta[b] + i] = lbuf[i];
  }
}

// one block per bucket: per-node counts -> LDS scan -> off[] + final srcs
__global__ __launch_bounds__(256) void k_bfinal(const int* __restrict__ boff,
                                                const int* __restrict__ ppack,
                                                int* __restrict__ off,
                                                int* __restrict__ srcs) {
  __shared__ int ncnt[128];
  __shared__ int nincl[128];
  int b = blockIdx.x, t = threadIdx.x;
  int e0 = boff[b], e1 = boff[b + 1];
  if (t < 128) ncnt[t] = 0;
  __syncthreads();
  for (int i = e0 + t; i < e1; i += 256) atomicAdd(&ncnt[((u32)ppack[i]) >> 20], 1);
  __syncthreads();
  if (t < 128) nincl[t] = ncnt[t];
  __syncthreads();
  for (int d = 1; d < 128; d <<= 1) {
    int x = 0;
    if (t < 128 && t >= d) x = nincl[t - d];
    __syncthreads();
    if (t < 128) nincl[t] += x;
    __syncthreads();
  }
  int node0 = b * 128;
  if (t < 128) {
    int excl = nincl[t] - ncnt[t];
    int node = node0 + t;
    if (node < NN) off[node] = e0 + excl;
    ncnt[t] = excl;  // becomes cursor (each thread touches only its own slot)
  }
  if (b == 0 && t == 0) off[NN] = NE;
  __syncthreads();
  for (int i = e0 + t; i < e1; i += 256) {
    u32 v = (u32)ppack[i];
    int dl = v >> 20;
    int pos = atomicAdd(&ncnt[dl], 1);
    srcs[e0 + pos] = (int)(v & 0xFFFFF);
  }
}

// ---------------- drug branch ----------------
__global__ __launch_bounds__(256) void k_conv(
    const int* __restrict__ xd, const float* __restrict__ emb,
    const float* __restrict__ convw, const float* __restrict__ convb,
    float* __restrict__ C) {
  __shared__ float e_s[100 * 128];
  __shared__ float w_s[4 * 800];
  __shared__ int xd_s[100];
  int t = threadIdx.x;
  int b = blockIdx.x >> 3;
  int og = (blockIdx.x & 7) << 2;
  if (t < 100) xd_s[t] = xd[b * 100 + t];
  __syncthreads();
  for (int i = t; i < 12800; i += 256)
    e_s[i] = emb[xd_s[i >> 7] * 128 + (i & 127)];
  for (int i = t; i < 3200; i += 256) w_s[i] = convw[og * 800 + i];
  __syncthreads();
  for (int idx = t; idx < 484; idx += 256) {
    int o = idx / 121, h = idx - o * 121;
    const float* wp = &w_s[o * 800];
    const float* ep = &e_s[h];
    float acc = 0.f;
    for (int i = 0; i < 100; i++) {
#pragma unroll
      for (int k = 0; k < 8; k++) acc += ep[i * 128 + k] * wp[i * 8 + k];
    }
    C[b * 3872 + (og + o) * 121 + h] = acc + convb[og + o];
  }
}

__global__ __launch_bounds__(256) void k_fcd(
    const float* __restrict__ C, const float* __restrict__ fcdw,
    const float* __restrict__ fcdb, float* __restrict__ XJ) {
  __shared__ float c_s[3872];
  __shared__ float red[128];
  int t = threadIdx.x, b = blockIdx.x;
  for (int i = t; i < 3872; i += 256) c_s[i] = C[b * 3872 + i];
  __syncthreads();
  int j = t & 127, half = t >> 7;
  float acc = 0.f;
  int k0 = half * 1936;
  for (int k = k0; k < k0 + 1936; k++) acc += c_s[k] * fcdw[k * 128 + j];
  if (half) red[j] = acc;
  __syncthreads();
  if (!half) XJ[b * 256 + j] = acc + red[j] + fcdb[j];
}

// ---------------- protein branch ----------------
__global__ __launch_bounds__(256) void k_z1(
    const float* __restrict__ xt, const float* __restrict__ w1,
    float* __restrict__ Z, float* __restrict__ pool) {
  __shared__ float xs[256 * FTD];
  __shared__ float w1s[FTD * DIM];
  int t = threadIdx.x;
  int base = blockIdx.x * 256;
  int g = base + t;
  if (g < NB * DIM) pool[g] = 0.f;
  for (int i = t; i < FTD * DIM; i += 256) w1s[i] = w1[i];
  int cnt = min(256, NN - base);
  for (int i = t; i < cnt * FTD; i += 256) xs[i] = xt[base * FTD + i];
  __syncthreads();
  int n = base + t;
  if (n < NN) {
    float acc[DIM];
#pragma unroll
    for (int j = 0; j < DIM; j++) acc[j] = 0.f;
    for (int k = 0; k < FTD; k++) {
      float xk = xs[t * FTD + k];
#pragma unroll
      for (int j = 0; j < DIM; j++) acc[j] += xk * w1s[k * DIM + j];
    }
    float* zp = &Z[n * DIM];
#pragma unroll
    for (int j = 0; j < DIM; j++) zp[j] = acc[j];
  }
}

// Fused GIN layer: 32 lanes per node, lane f owns feature f.
// Gather in fixed 32-iteration chunks with 4 accumulators (deep ILP).
template <int HAS_NEXT, int DO_POOL>
__global__ __launch_bounds__(256) void k_gin(
    const int* __restrict__ off, const int* __restrict__ srcs,
    const float* __restrict__ Zin, const float* __restrict__ b1,
    const float* __restrict__ w2, const float* __restrict__ b2,
    const float* __restrict__ bng, const float* __restrict__ bnb,
    const float* __restrict__ bnrm, const float* __restrict__ bnrv,
    const float* __restrict__ w1n, float* __restrict__ Zout,
    float* __restrict__ pool, const int* __restrict__ batch) {
  int t = threadIdx.x;
  int f = t & 31;
  int n = blockIdx.x * 8 + (t >> 5);  // grid*8 == NN exactly
  int beg = off[n], end = off[n + 1];
  float a0 = Zin[n * DIM + f], a1 = 0.f, a2 = 0.f, a3 = 0.f;
  for (int base = beg; base < end; base += 32) {
    int idx = base + f;
    int sv = (idx < end) ? srcs[idx] : -1;
#pragma unroll
    for (int k = 0; k < 32; k += 4) {
      int s0 = __shfl(sv, k, 32);
      int s1 = __shfl(sv, k + 1, 32);
      int s2 = __shfl(sv, k + 2, 32);
      int s3 = __shfl(sv, k + 3, 32);
      float v0 = Zin[max(s0, 0) * DIM + f];
      float v1 = Zin[max(s1, 0) * DIM + f];
      float v2 = Zin[max(s2, 0) * DIM + f];
      float v3 = Zin[max(s3, 0) * DIM + f];
      a0 += (s0 >= 0) ? v0 : 0.f;
      a1 += (s1 >= 0) ? v1 : 0.f;
      a2 += (s2 >= 0) ? v2 : 0.f;
      a3 += (s3 >= 0) ? v3 : 0.f;
    }
  }
  float acc = (a0 + a1) + (a2 + a3);
  float hid = fmaxf(acc + b1[f], 0.f);
  float o = b2[f];
#pragma unroll
  for (int k = 0; k < DIM; k++) o += __shfl(hid, k, 32) * w2[k * DIM + f];
  float sc = bng[f] * rsqrtf(bnrv[f] + 1e-5f);
  float hn = fmaxf(o, 0.f) * sc + (bnb[f] - bnrm[f] * sc);
  if (HAS_NEXT) {
    float z = 0.f;
#pragma unroll
    for (int k = 0; k < DIM; k++) z += __shfl(hn, k, 32) * w1n[k * DIM + f];
    Zout[n * DIM + f] = z;
  }
  if (DO_POOL) atomicAdd(&pool[batch[n] * DIM + f], hn);
}

__global__ __launch_bounds__(128) void k_fct(
    const float* __restrict__ pool, const float* __restrict__ fctw,
    const float* __restrict__ fctb, float* __restrict__ XJ) {
  __shared__ float p_s[DIM];
  int t = threadIdx.x, b = blockIdx.x;
  if (t < DIM) p_s[t] = pool[b * DIM + t];
  __syncthreads();
  float acc = fctb[t];
  for (int k = 0; k < DIM; k++) acc += p_s[k] * fctw[k * 128 + t];
  XJ[b * 256 + 128 + t] = fmaxf(acc, 0.f);
}

__global__ __launch_bounds__(256) void k_c1(
    const float* __restrict__ XJ, const float* __restrict__ w,
    const float* __restrict__ bias, float* __restrict__ H1) {
  __shared__ float xs[256];
  int t = threadIdx.x, b = blockIdx.y;
  xs[t] = XJ[b * 256 + t];
  __syncthreads();
  int j = blockIdx.x * 256 + t;
  float acc = bias[j];
  for (int k = 0; k < 256; k++) acc += xs[k] * w[k * 1024 + j];
  H1[b * 1024 + j] = fmaxf(acc, 0.f);
}

__global__ __launch_bounds__(256) void k_c2(
    const float* __restrict__ H1, const float* __restrict__ w,
    const float* __restrict__ bias, float* __restrict__ H2) {
  __shared__ float hs[1024];
  int t = threadIdx.x, b = blockIdx.x;
  for (int i = t; i < 1024; i += 256) hs[i] = H1[b * 1024 + i];
  __syncthreads();
  float acc = bias[t];
  for (int k = 0; k < 1024; k++) acc += hs[k] * w[k * 256 + t];
  H2[b * 256 + t] = fmaxf(acc, 0.f);
}

__global__ __launch_bounds__(64) void k_c3(
    const float* __restrict__ H2, const float* __restrict__ w,
    const float* __restrict__ bias, const float* __restrict__ y,
    float* __restrict__ out) {
  int b = blockIdx.x * 64 + threadIdx.x;
  float acc = bias[0];
  for (int k = 0; k < 256; k++) acc += H2[b * 256 + k] * w[k];
  out[b] = acc;
  out[NB + b] = y[b];
}

extern "C" void kernel_launch(void* const* d_in, const int* in_sizes, int n_in,
                              void* d_out, int out_size, void* d_ws,
                              size_t ws_size, hipStream_t stream) {
  const int* xd = (const int*)d_in[0];
  const float* xt = (const float*)d_in[1];
  const int* ei = (const int*)d_in[2];
  const int* batch = (const int*)d_in[3];
  const float* y = (const float*)d_in[4];
  const float* emb = (const float*)d_in[5];
  const float* convw = (const float*)d_in[6];
  const float* convb = (const float*)d_in[7];
  const float* fcdw = (const float*)d_in[8];
  const float* fcdb = (const float*)d_in[9];
  const float* g1w1 = (const float*)d_in[10];
  const float* g1b1 = (const float*)d_in[11];
  const float* g1w2 = (const float*)d_in[12];
  const float* g1b2 = (const float*)d_in[13];
  const float* gw1 = (const float*)d_in[14];
  const float* gb1 = (const float*)d_in[15];
  const float* gw2 = (const float*)d_in[16];
  const float* gb2 = (const float*)d_in[17];
  const float* bng = (const float*)d_in[18];
  const float* bnb = (const float*)d_in[19];
  const float* bnrm = (const float*)d_in[20];
  const float* bnrv = (const float*)d_in[21];
  const float* fctw = (const float*)d_in[22];
  const float* fctb = (const float*)d_in[23];
  const float* c1w = (const float*)d_in[24];
  const float* c1b = (const float*)d_in[25];
  const float* c2w = (const float*)d_in[26];
  const float* c2b = (const float*)d_in[27];
  const float* c3w = (const float*)d_in[28];
  const float* c3b = (const float*)d_in[29];
  float* out = (float*)d_out;

  float* ws = (float*)d_ws;
  float* Z0 = ws;                            // NN*32 f32
  float* Z1 = Z0 + (size_t)NN * DIM;         // NN*32 f32
  int* srcs = (int*)(Z1 + (size_t)NN * DIM); // NE int
  int* off = srcs + NE;                      // NN+1
  int* bcnt = off + NN + 1;                  // NBK
  int* boff = bcnt + NBK;                    // NBK+1
  int* bcur = boff + NBK + 1;                // NBK
  // union region: ppack (CSR build) aliases drug/classifier temps
  // (safe: all launches below are stream-ordered; ppack dead after k_bfinal)
  int* ppack = bcur + NBK;                   // NE int
  float* C = (float*)ppack;                  // 256*3872
  float* XJ = C + (size_t)NB * 3872;         // 256*256
  float* H1 = XJ + NB * 256;                 // 256*1024
  float* H2 = H1 + NB * 1024;                // 256*256
  float* POOL = H2 + NB * 256;               // 256*32

  int nblk = (NN + 255) / 256;

  // CSR build (edge list is layer-invariant)
  k_bzero<<<(NBK + 255) / 256, 256, 0, stream>>>(bcnt);
  k_bhist<<<512, 256, 0, stream>>>(ei, bcnt);
  k_bscan<<<1, 1024, 0, stream>>>(bcnt, boff, bcur);
  k_bscatter<<<NE / SCHUNK, 256, 0, stream>>>(ei, bcur, ppack);
  k_bfinal<<<NBK, 256, 0, stream>>>(boff, ppack, off, srcs);

  // drug branch (reuses ppack region — after k_bfinal, stream-ordered)
  k_conv<<<NB * 8, 256, 0, stream>>>(xd, emb, convw, convb, C);
  k_fcd<<<NB, 256, 0, stream>>>(C, fcdw, fcdb, XJ);

  // protein branch
  k_z1<<<nblk, 256, 0, stream>>>(xt, g1w1, Z0, POOL);
  float* zin = Z0;
  float* zout = Z1;
  for (int i = 0; i < 5; i++) {
    const float *b1, *w2, *b2;
    if (i == 0) { b1 = g1b1; w2 = g1w2; b2 = g1b2; }
    else {
      b1 = gb1 + (i - 1) * DIM;
      w2 = gw2 + (i - 1) * DIM * DIM;
      b2 = gb2 + (i - 1) * DIM;
    }
    const float* w1n = gw1 + i * DIM * DIM;  // only read when i<4
    if (i < 4)
      k_gin<1, 0><<<NN / 8, 256, 0, stream>>>(
          off, srcs, zin, b1, w2, b2, bng + i * DIM, bnb + i * DIM,
          bnrm + i * DIM, bnrv + i * DIM, w1n, zout, POOL, batch);
    else
      k_gin<0, 1><<<NN / 8, 256, 0, stream>>>(
          off, srcs, zin, b1, w2, b2, bng + i * DIM, bnb + i * DIM,
          bnrm + i * DIM, bnrv + i * DIM, w1n, zout, POOL, batch);
    float* tmp = zin; zin = zout; zout = tmp;
  }
  k_fct<<<NB, 128, 0, stream>>>(POOL, fctw, fctb, XJ);
  k_c1<<<dim3(4, NB), 256, 0, stream>>>(XJ, c1w, c1b, H1);
  k_c2<<<NB, 256, 0, stream>>>(H1, c2w, c2b, H2);
  k_c3<<<4, 64, 0, stream>>>(H2, c3w, c3b, y, out);
}